// Round 8
// baseline (557.354 us; speedup 1.0000x reference)
//
#include <hip/hip_runtime.h>
#include <math.h>

#define NN 50000
#define EE 800000
#define ET 850000   // EE + NN (self loops appended)
#define DD 128
#define GG 1000
#define SLOPE 0.2f

#define KB   2048          // edges per phase-A block
#define NBA  416           // ceil(ET/KB)
#define BSZ  4096          // positions per bucket
#define NBUK 208           // ceil(ET/BSZ)

typedef unsigned int  u32;
typedef unsigned short u16;

// fp16 pack/unpack (hardware cvt, round-to-nearest-even)
__device__ __forceinline__ u16 f2h(float f){
  return __builtin_bit_cast(unsigned short, (_Float16)f);
}
__device__ __forceinline__ float hlo(u32 d){
  return (float)__builtin_bit_cast(_Float16, (unsigned short)(d & 0xFFFFu));
}
__device__ __forceinline__ float hhi(u32 d){
  return (float)__builtin_bit_cast(_Float16, (unsigned short)(d >> 16));
}

// ---------------- init: cnt=0, bcur=0, graph boundaries ----------------
__global__ void init_k(const int* __restrict__ batchs, int* __restrict__ cnt,
                       int* __restrict__ gstart, int* __restrict__ bcur){
  int n = blockIdx.x*256 + threadIdx.x;
  if (n < NBUK) bcur[n] = 0;
  if (n < NN){
    cnt[n] = 0;
    int b = batchs[n];
    int prev = n ? batchs[n-1] : -1;
    for (int g = prev+1; g <= b; ++g) gstart[g] = n;
    if (n == NN-1){
      for (int g = b+1; g <= GG; ++g) gstart[g] = NN;
    }
  }
}

// count + per-edge rank (atomicAdd return)
__global__ void count_k(const int* __restrict__ ei, int* __restrict__ cnt,
                        int* __restrict__ rank){
  int e = blockIdx.x*256 + threadIdx.x;
  if (e < ET){
    int d = (e < EE) ? ei[EE + e] : (e - EE);
    rank[e] = atomicAdd(&cnt[d], 1);
  }
}

__global__ __launch_bounds__(256) void blocksum_k(const int* __restrict__ cnt,
                                                  int* __restrict__ bsum){
  int i = blockIdx.x*256 + threadIdx.x;
  int v = (i < NN) ? cnt[i] : 0;
  #pragma unroll
  for (int o=32;o;o>>=1) v += __shfl_xor(v,o);
  __shared__ int ws[4];
  if ((threadIdx.x & 63) == 0) ws[threadIdx.x>>6] = v;
  __syncthreads();
  if (threadIdx.x == 0) bsum[blockIdx.x] = ws[0]+ws[1]+ws[2]+ws[3];
}

__global__ __launch_bounds__(256) void scanb_k(int* __restrict__ bsum, int nb){
  int tid = threadIdx.x;
  int v = (tid < nb) ? bsum[tid] : 0;
  int lane = tid & 63, wv = tid >> 6;
  int s = v;
  #pragma unroll
  for (int o=1;o<64;o<<=1){ int t = __shfl_up(s,o); if (lane>=o) s += t; }
  __shared__ int ws[4];
  if (lane == 63) ws[wv] = s;
  __syncthreads();
  int woff = 0;
  for (int k=0;k<wv;++k) woff += ws[k];
  if (tid < nb) bsum[tid] = s - v + woff;   // exclusive prefix
}

__global__ __launch_bounds__(256) void scatter_k(const int* __restrict__ cnt,
                                                 const int* __restrict__ bsum,
                                                 int* __restrict__ row_start){
  int i = blockIdx.x*256 + threadIdx.x;
  int v = (i < NN) ? cnt[i] : 0;
  int lane = threadIdx.x & 63, wv = threadIdx.x >> 6;
  int s = v;
  #pragma unroll
  for (int o=1;o<64;o<<=1){ int t = __shfl_up(s,o); if (lane>=o) s += t; }
  __shared__ int ws[4];
  if (lane == 63) ws[wv] = s;
  __syncthreads();
  int woff = 0;
  for (int k=0;k<wv;++k) woff += ws[k];
  int off = s - v + woff + bsum[blockIdx.x];
  if (i < NN) row_start[i] = off;
  if (i == 0) row_start[NN] = ET;
}

// ---- phase A: partition (pos,src) pairs into fixed 4096-wide pos-buckets ----
__global__ __launch_bounds__(256) void partA_k(const int* __restrict__ ei,
                                               const int* __restrict__ rank,
                                               const int* __restrict__ row_start,
                                               int* __restrict__ bcur,
                                               uint2* __restrict__ stage){
  __shared__ uint2 lpairs[KB];          // 16 KB
  __shared__ int lcnt[256], lstart[256], lrun[256], gbase[256];
  __shared__ int ws[4];
  int tid = threadIdx.x;
  int base = blockIdx.x * KB;
  int nE = min(KB, ET - base);
  lcnt[tid] = 0;
  __syncthreads();
  u32 pos_r[KB/256]; u32 src_r[KB/256];
  #pragma unroll
  for (int i=0;i<KB/256;++i){
    int e = base + i*256 + tid;
    u32 p = 0xFFFFFFFFu, s = 0;
    if (e < ET){
      int d, sr;
      if (e < EE){ sr = ei[e]; d = ei[EE + e]; }
      else       { sr = e - EE; d = sr; }
      p = (u32)(row_start[d] + rank[e]);
      s = (u32)sr;
      atomicAdd(&lcnt[p >> 12], 1);
    }
    pos_r[i] = p; src_r[i] = s;
  }
  __syncthreads();
  int v = lcnt[tid];
  int lane = tid & 63, wv = tid >> 6;
  int s = v;
  #pragma unroll
  for (int o=1;o<64;o<<=1){ int t = __shfl_up(s,o); if (lane>=o) s += t; }
  if (lane == 63) ws[wv] = s;
  __syncthreads();
  int woff = 0;
  for (int k=0;k<wv;++k) woff += ws[k];
  int excl = s - v + woff;
  lstart[tid] = excl;
  lrun[tid]   = excl;
  gbase[tid]  = (tid < NBUK && v > 0) ? atomicAdd(&bcur[tid], v) : 0;
  __syncthreads();
  #pragma unroll
  for (int i=0;i<KB/256;++i){
    if (pos_r[i] != 0xFFFFFFFFu){
      int b = pos_r[i] >> 12;
      int slot = atomicAdd(&lrun[b], 1);
      lpairs[slot] = make_uint2(pos_r[i], src_r[i]);
    }
  }
  __syncthreads();
  for (int j = tid; j < nE; j += 256){
    uint2 pr = lpairs[j];
    int b = pr.x >> 12;
    int dest = (b << 12) + gbase[b] + (j - lstart[b]);
    stage[dest] = pr;
  }
}

// ---- phase B: assemble each 16KB srcs window in LDS, stream out coalesced ----
__global__ __launch_bounds__(256) void partB_k(const uint2* __restrict__ stage,
                                               int* __restrict__ srcs){
  __shared__ int buf[BSZ];              // 16 KB
  int b = blockIdx.x, tid = threadIdx.x;
  int base = b << 12;
  int n_b = min(BSZ, ET - base);
  for (int j = tid; j < n_b; j += 256){
    uint2 pr = stage[base + j];
    buf[pr.x - base] = (int)pr.y;
  }
  __syncthreads();
  for (int j = tid; j*4 < n_b; j += 256){
    *(int4*)(srcs + base + j*4) = *(const int4*)(buf + j*4);
  }
}

// ------- register-blocked GEMM: C[N,128] = A[N,128] @ W[128,128] ---------
// 64 rows/block, 256 threads, thread tile 4x8, K panels of 16, double-buffered
// small LDS (24.5 KB -> 6 blocks/CU). Fused rowdot epilogue (hs, hd in f32).
// H16: store C as fp16 (layers 3,4) else f32.
template<bool H16>
__global__ __launch_bounds__(256) void gemm_rb_k(const float* __restrict__ A,
                                                 const float* __restrict__ W,
                                                 const float* __restrict__ as,
                                                 const float* __restrict__ ad,
                                                 void* __restrict__ Cout,
                                                 float* __restrict__ hs,
                                                 float* __restrict__ hd){
  __shared__ float As[2][16][68];     // [buf][k][row], pad 68
  __shared__ float Wsh[2][16][128];   // [buf][k][col]
  int tid = threadIdx.x;
  int rbase = blockIdx.x*64;
  int ty = tid >> 4, tx = tid & 15;   // rows ty*4.., cols tx*8..
  int arow = tid >> 2, aq = tid & 3;  // A stage: row, k-quad
  int wk = tid >> 5, wc = tid & 31;   // W stage: k-row, col-quad

  float4 aReg, w0Reg, w1Reg;
  {
    int r = rbase + arow;
    aReg = (r < NN) ? *(const float4*)(A + (size_t)r*DD + aq*4) : float4{0,0,0,0};
    w0Reg = *(const float4*)(W + (size_t)wk*DD + wc*4);
    w1Reg = *(const float4*)(W + (size_t)(wk+8)*DD + wc*4);
  }
  As[0][aq*4+0][arow] = aReg.x;
  As[0][aq*4+1][arow] = aReg.y;
  As[0][aq*4+2][arow] = aReg.z;
  As[0][aq*4+3][arow] = aReg.w;
  *(float4*)(&Wsh[0][wk][wc*4])   = w0Reg;
  *(float4*)(&Wsh[0][wk+8][wc*4]) = w1Reg;
  __syncthreads();

  float acc[4][8] = {};
  for (int t=0; t<8; ++t){
    int cur = t & 1;
    if (t < 7){
      int k0 = (t+1)*16;
      int r = rbase + arow;
      aReg = (r < NN) ? *(const float4*)(A + (size_t)r*DD + k0 + aq*4) : float4{0,0,0,0};
      w0Reg = *(const float4*)(W + (size_t)(k0+wk)*DD + wc*4);
      w1Reg = *(const float4*)(W + (size_t)(k0+wk+8)*DD + wc*4);
    }
    #pragma unroll
    for (int k=0;k<16;++k){
      float4 a4  = *(const float4*)(&As[cur][k][ty*4]);
      float4 wA  = *(const float4*)(&Wsh[cur][k][tx*8]);
      float4 wB  = *(const float4*)(&Wsh[cur][k][tx*8+4]);
      float a[4] = {a4.x, a4.y, a4.z, a4.w};
      float wv[8] = {wA.x, wA.y, wA.z, wA.w, wB.x, wB.y, wB.z, wB.w};
      #pragma unroll
      for (int ii=0;ii<4;++ii)
        #pragma unroll
        for (int jj=0;jj<8;++jj)
          acc[ii][jj] += a[ii]*wv[jj];
    }
    if (t < 7){
      __syncthreads();
      int nxt = cur ^ 1;
      As[nxt][aq*4+0][arow] = aReg.x;
      As[nxt][aq*4+1][arow] = aReg.y;
      As[nxt][aq*4+2][arow] = aReg.z;
      As[nxt][aq*4+3][arow] = aReg.w;
      *(float4*)(&Wsh[nxt][wk][wc*4])   = w0Reg;
      *(float4*)(&Wsh[nxt][wk+8][wc*4]) = w1Reg;
      __syncthreads();
    }
  }

  // fused rowdot epilogue: hs/hd from f32 accumulators (alphas stay exact)
  float4 s0 = *(const float4*)(as + tx*8);
  float4 s1 = *(const float4*)(as + tx*8 + 4);
  float4 d0 = *(const float4*)(ad + tx*8);
  float4 d1 = *(const float4*)(ad + tx*8 + 4);
  #pragma unroll
  for (int ii=0;ii<4;++ii){
    float ds = acc[ii][0]*s0.x + acc[ii][1]*s0.y + acc[ii][2]*s0.z + acc[ii][3]*s0.w
             + acc[ii][4]*s1.x + acc[ii][5]*s1.y + acc[ii][6]*s1.z + acc[ii][7]*s1.w;
    float dd = acc[ii][0]*d0.x + acc[ii][1]*d0.y + acc[ii][2]*d0.z + acc[ii][3]*d0.w
             + acc[ii][4]*d1.x + acc[ii][5]*d1.y + acc[ii][6]*d1.z + acc[ii][7]*d1.w;
    #pragma unroll
    for (int o=1;o<16;o<<=1){ ds += __shfl_xor(ds,o); dd += __shfl_xor(dd,o); }
    int r = rbase + ty*4 + ii;
    if (tx == 0 && r < NN){ hs[r] = ds; hd[r] = dd; }
  }
  // C store
  #pragma unroll
  for (int ii=0;ii<4;++ii){
    int r = rbase + ty*4 + ii;
    if (r < NN){
      if constexpr (H16){
        u16* C = (u16*)Cout;
        ushort4 o0 = {f2h(acc[ii][0]), f2h(acc[ii][1]), f2h(acc[ii][2]), f2h(acc[ii][3])};
        ushort4 o1 = {f2h(acc[ii][4]), f2h(acc[ii][5]), f2h(acc[ii][6]), f2h(acc[ii][7])};
        *(ushort4*)(C + (size_t)r*DD + tx*8)     = o0;
        *(ushort4*)(C + (size_t)r*DD + tx*8 + 4) = o1;
      } else {
        float* C = (float*)Cout;
        float4 o0 = {acc[ii][0], acc[ii][1], acc[ii][2], acc[ii][3]};
        float4 o1 = {acc[ii][4], acc[ii][5], acc[ii][6], acc[ii][7]};
        *(float4*)(C + (size_t)r*DD + tx*8)     = o0;
        *(float4*)(C + (size_t)r*DD + tx*8 + 4) = o1;
      }
    }
  }
}

// ---- agg (f32 h): one wave per node, half-wave parity split ----
__global__ __launch_bounds__(256) void gat_agg_f_k(const float* __restrict__ h,
                                                   const float* __restrict__ hs,
                                                   const float* __restrict__ hd,
                                                   const int* __restrict__ row_start,
                                                   const int* __restrict__ srcs,
                                                   const float* __restrict__ bias,
                                                   float* __restrict__ out){
  int node = blockIdx.x*4 + (threadIdx.x >> 6);
  int lane = threadIdx.x & 63;
  if (node >= NN) return;
  int half = lane >> 5;
  int hl   = lane & 31;
  int beg = row_start[node], end = row_start[node+1];
  float hdn = hd[node];
  float m = -INFINITY, denom = 0.f;
  float4 acc = {0.f,0.f,0.f,0.f};
  for (int c=beg; c<end; c+=64){
    int nc = min(64, end-c);
    float e = -INFINITY; int src = 0;
    if (lane < nc){
      src = srcs[c+lane];
      float t = hs[src] + hdn;
      e = (t >= 0.f) ? t : SLOPE*t;
    }
    float cm = e;
    #pragma unroll
    for (int o=32;o;o>>=1) cm = fmaxf(cm, __shfl_xor(cm,o));
    float nm = fmaxf(m, cm);
    float w = (lane < nc) ? expf(e - nm) : 0.f;
    float cs = w;
    #pragma unroll
    for (int o=32;o;o>>=1) cs += __shfl_xor(cs,o);
    float scale = expf(m - nm);
    denom = denom*scale + cs;
    acc.x *= scale; acc.y *= scale; acc.z *= scale; acc.w *= scale;
    m = nm;
    int nh = (nc + 1 - half) >> 1;
    for (int i=0;i<nh;++i){
      int j = 2*i + half;
      float wi = __shfl(w, j);
      int   si = __shfl(src, j);
      float4 hv = *(const float4*)(h + (size_t)si*DD + hl*4);
      acc.x += wi*hv.x; acc.y += wi*hv.y; acc.z += wi*hv.z; acc.w += wi*hv.w;
    }
  }
  acc.x += __shfl_xor(acc.x, 32);
  acc.y += __shfl_xor(acc.y, 32);
  acc.z += __shfl_xor(acc.z, 32);
  acc.w += __shfl_xor(acc.w, 32);
  if (half == 0){
    float inv = 1.f/denom;
    float4 b4 = *(const float4*)(bias + hl*4);
    float4 o4;
    o4.x = fmaxf(acc.x*inv + b4.x, 0.f);
    o4.y = fmaxf(acc.y*inv + b4.y, 0.f);
    o4.z = fmaxf(acc.z*inv + b4.z, 0.f);
    o4.w = fmaxf(acc.w*inv + b4.w, 0.f);
    *(float4*)(out + (size_t)node*DD + hl*4) = o4;
  }
}

// ---- agg (fp16 h): same structure, uint2 (4 fp16) per lane --------------
__global__ __launch_bounds__(256) void gat_agg_h_k(const u16* __restrict__ hh,
                                                   const float* __restrict__ hs,
                                                   const float* __restrict__ hd,
                                                   const int* __restrict__ row_start,
                                                   const int* __restrict__ srcs,
                                                   const float* __restrict__ bias,
                                                   float* __restrict__ out){
  int node = blockIdx.x*4 + (threadIdx.x >> 6);
  int lane = threadIdx.x & 63;
  if (node >= NN) return;
  int half = lane >> 5;
  int hl   = lane & 31;
  int beg = row_start[node], end = row_start[node+1];
  float hdn = hd[node];
  float m = -INFINITY, denom = 0.f;
  float a0=0.f, a1=0.f, a2=0.f, a3=0.f;
  for (int c=beg; c<end; c+=64){
    int nc = min(64, end-c);
    float e = -INFINITY; int src = 0;
    if (lane < nc){
      src = srcs[c+lane];
      float t = hs[src] + hdn;
      e = (t >= 0.f) ? t : SLOPE*t;
    }
    float cm = e;
    #pragma unroll
    for (int o=32;o;o>>=1) cm = fmaxf(cm, __shfl_xor(cm,o));
    float nm = fmaxf(m, cm);
    float w = (lane < nc) ? expf(e - nm) : 0.f;
    float cs = w;
    #pragma unroll
    for (int o=32;o;o>>=1) cs += __shfl_xor(cs,o);
    float scale = expf(m - nm);
    denom = denom*scale + cs;
    a0 *= scale; a1 *= scale; a2 *= scale; a3 *= scale;
    m = nm;
    int nh = (nc + 1 - half) >> 1;
    for (int i=0;i<nh;++i){
      int j = 2*i + half;
      float wi = __shfl(w, j);
      int   si = __shfl(src, j);
      uint2 hv = *(const uint2*)(hh + (size_t)si*DD + hl*4);
      a0 += wi*hlo(hv.x); a1 += wi*hhi(hv.x);
      a2 += wi*hlo(hv.y); a3 += wi*hhi(hv.y);
    }
  }
  a0 += __shfl_xor(a0, 32);
  a1 += __shfl_xor(a1, 32);
  a2 += __shfl_xor(a2, 32);
  a3 += __shfl_xor(a3, 32);
  if (half == 0){
    float inv = 1.f/denom;
    float4 b4 = *(const float4*)(bias + hl*4);
    float4 o4;
    o4.x = fmaxf(a0*inv + b4.x, 0.f);
    o4.y = fmaxf(a1*inv + b4.y, 0.f);
    o4.z = fmaxf(a2*inv + b4.z, 0.f);
    o4.w = fmaxf(a3*inv + b4.w, 0.f);
    *(float4*)(out + (size_t)node*DD + hl*4) = o4;
  }
}

// ---- fused tail: pool + lin0 + lin1(+energy,residual) + lins + head -----
__global__ __launch_bounds__(128) void tail_k(const float* __restrict__ h,
                                              const int* __restrict__ gstart,
                                              const float* __restrict__ energy,
                                              const float* __restrict__ W0, const float* __restrict__ b0,
                                              const float* __restrict__ W1, const float* __restrict__ b1,
                                              const float* __restrict__ W2, const float* __restrict__ b2,
                                              const float* __restrict__ W3, const float* __restrict__ b3,
                                              float* __restrict__ out){
  __shared__ float row[DD];
  __shared__ float buf[DD];
  int gr = blockIdx.x, j = threadIdx.x;
  int beg = gstart[gr], end = gstart[gr+1];
  float s = 0.f;
  for (int n=beg; n<end; ++n) s += h[(size_t)n*DD + j];
  row[j] = s;
  __syncthreads();
  float acc = 0.f;
  #pragma unroll 8
  for (int k=0;k<DD;++k) acc += row[k]*W0[k*DD + j];
  float y = fmaxf(acc + b0[j], 0.f);
  buf[j] = y;
  __syncthreads();
  acc = 0.f;
  #pragma unroll 8
  for (int k=0;k<DD;++k) acc += buf[k]*W1[k*DD + j];
  acc += energy[gr]*W1[DD*DD + j];
  float z = fmaxf(acc + b1[j], 0.f) + y;
  __syncthreads();
  row[j] = z;
  __syncthreads();
  acc = 0.f;
  #pragma unroll 8
  for (int k=0;k<DD;++k) acc += row[k]*W2[k*DD + j];
  float z2 = fmaxf(acc + b2[j], 0.f);
  buf[j] = z2;
  __syncthreads();
  if (j < 64){
    float z0 = buf[j], z1 = buf[j+64];
    float l0 = z0*W3[j*2]     + z1*W3[(j+64)*2];
    float l1 = z0*W3[j*2 + 1] + z1*W3[(j+64)*2 + 1];
    #pragma unroll
    for (int o=32;o;o>>=1){ l0 += __shfl_xor(l0,o); l1 += __shfl_xor(l1,o); }
    if (j == 0){
      l0 += b3[0]; l1 += b3[1];
      float mx = fmaxf(l0, l1);
      float lse = mx + logf(expf(l0-mx) + expf(l1-mx));
      out[gr*2]   = l0 - lse;
      out[gr*2+1] = l1 - lse;
    }
  }
}

extern "C" void kernel_launch(void* const* d_in, const int* in_sizes, int n_in,
                              void* d_out, int out_size, void* d_ws, size_t ws_size,
                              hipStream_t stream) {
  const float* x      = (const float*)d_in[0];
  const float* energy = (const float*)d_in[1];
  const float* W1     = (const float*)d_in[2];
  const float* as1    = (const float*)d_in[3];
  const float* ad1    = (const float*)d_in[4];
  const float* b1     = (const float*)d_in[5];
  const float* Ws     = (const float*)d_in[6];
  const float* ass    = (const float*)d_in[7];
  const float* ads    = (const float*)d_in[8];
  const float* bs     = (const float*)d_in[9];
  const float* lin0_W = (const float*)d_in[10];
  const float* lin0_b = (const float*)d_in[11];
  const float* lin1_W = (const float*)d_in[12];
  const float* lin1_b = (const float*)d_in[13];
  const float* lins_W = (const float*)d_in[14];
  const float* lins_b = (const float*)d_in[15];
  const float* lin3_W = (const float*)d_in[16];
  const float* lin3_b = (const float*)d_in[17];
  const int*   ei     = (const int*)d_in[18];
  const int*   batchs = (const int*)d_in[19];
  float* out = (float*)d_out;

  char* wp = (char*)d_ws;
  auto alloc = [&](size_t bytes)->void*{
    void* p = (void*)wp;
    wp += (bytes + 255) & ~(size_t)255;
    return p;
  };
  float* hA        = (float*)alloc((size_t)NN*DD*4);   // agg output (f32)
  float* hB        = (float*)alloc((size_t)NN*DD*4);   // gemm out f32 (layers 1,2)
  u16*   hHf       = (u16*)hB;                         // fp16 view (layers 3,4)
  float* hs        = (float*)alloc((size_t)NN*4);
  float* hd        = (float*)alloc((size_t)NN*4);
  int*   cnt       = (int*)alloc((size_t)NN*4);
  int*   row_start = (int*)alloc((size_t)(NN+1)*4);
  int*   rank      = (int*)alloc((size_t)ET*4);
  int*   srcs      = (int*)alloc((size_t)ET*4);
  uint2* stage     = (uint2*)alloc((size_t)NBUK*BSZ*8);
  int*   bcur      = (int*)alloc((size_t)NBUK*4);
  int*   gstart    = (int*)alloc((size_t)(GG+1)*4);
  int*   bsum      = (int*)alloc((size_t)256*4);

  const int NB_N  = (NN + 255)/256;     // 196
  const int NB_E  = (ET + 255)/256;     // 3321
  const int NB_W  = (NN + 3)/4;         // 12500 (wave per node)
  const int NB_G  = (NN + 63)/64;       // 782 gemm blocks

  // CSR + graph boundaries (two-phase bucketed scatter)
  init_k<<<NB_N, 256, 0, stream>>>(batchs, cnt, gstart, bcur);
  count_k<<<NB_E, 256, 0, stream>>>(ei, cnt, rank);
  blocksum_k<<<NB_N, 256, 0, stream>>>(cnt, bsum);
  scanb_k<<<1, 256, 0, stream>>>(bsum, NB_N);
  scatter_k<<<NB_N, 256, 0, stream>>>(cnt, bsum, row_start);
  partA_k<<<NBA, 256, 0, stream>>>(ei, rank, row_start, bcur, stage);
  partB_k<<<NBUK, 256, 0, stream>>>(stage, srcs);

  // layers 1,2: f32 gather path
  gemm_rb_k<false><<<NB_G, 256, 0, stream>>>(x, W1, as1, ad1, (void*)hB, hs, hd);
  gat_agg_f_k<<<NB_W, 256, 0, stream>>>(hB, hs, hd, row_start, srcs, b1, hA);
  gemm_rb_k<false><<<NB_G, 256, 0, stream>>>(hA, Ws, ass, ads, (void*)hB, hs, hd);
  gat_agg_f_k<<<NB_W, 256, 0, stream>>>(hB, hs, hd, row_start, srcs, bs, hA);

  // layers 3,4: fp16 gather path (alphas stay f32)
  gemm_rb_k<true><<<NB_G, 256, 0, stream>>>(hA, Ws + (size_t)1*DD*DD, ass + DD, ads + DD,
                                            (void*)hHf, hs, hd);
  gat_agg_h_k<<<NB_W, 256, 0, stream>>>(hHf, hs, hd, row_start, srcs, bs + DD, hA);
  gemm_rb_k<true><<<NB_G, 256, 0, stream>>>(hA, Ws + (size_t)2*DD*DD, ass + 2*DD, ads + 2*DD,
                                            (void*)hHf, hs, hd);
  gat_agg_h_k<<<NB_W, 256, 0, stream>>>(hHf, hs, hd, row_start, srcs, bs + 2*DD, hA);

  // fused tail
  tail_k<<<GG, 128, 0, stream>>>(hA, gstart, energy,
                                 lin0_W, lin0_b, lin1_W, lin1_b,
                                 lins_W, lins_b, lin3_W, lin3_b, out);
}

// Round 11
// 525.201 us; speedup vs baseline: 1.0612x; 1.0612x over previous
//
#include <hip/hip_runtime.h>
#include <math.h>

#define NN 50000
#define EE 800000
#define ET 850000   // EE + NN (self loops appended)
#define DD 128
#define GG 1000
#define SLOPE 0.2f

#define KB   2048          // edges per phase-A block
#define NBA  416           // ceil(ET/KB)
#define BSZ  4096          // positions per bucket
#define NBUK 208           // ceil(ET/BSZ)

typedef unsigned int  u32;
typedef unsigned short u16;

// fp16 pack/unpack (hardware cvt, round-to-nearest-even)
__device__ __forceinline__ u16 f2h(float f){
  return __builtin_bit_cast(unsigned short, (_Float16)f);
}
__device__ __forceinline__ float hlo(u32 d){
  return (float)__builtin_bit_cast(_Float16, (unsigned short)(d & 0xFFFFu));
}
__device__ __forceinline__ float hhi(u32 d){
  return (float)__builtin_bit_cast(_Float16, (unsigned short)(d >> 16));
}

// ---------------- init: cnt=0, bcur=0, graph boundaries ----------------
__global__ void init_k(const int* __restrict__ batchs, int* __restrict__ cnt,
                       int* __restrict__ gstart, int* __restrict__ bcur){
  int n = blockIdx.x*256 + threadIdx.x;
  if (n < NBUK) bcur[n] = 0;
  if (n < NN){
    cnt[n] = 0;
    int b = batchs[n];
    int prev = n ? batchs[n-1] : -1;
    for (int g = prev+1; g <= b; ++g) gstart[g] = n;
    if (n == NN-1){
      for (int g = b+1; g <= GG; ++g) gstart[g] = NN;
    }
  }
}

// count + per-edge rank (atomicAdd return)
__global__ void count_k(const int* __restrict__ ei, int* __restrict__ cnt,
                        int* __restrict__ rank){
  int e = blockIdx.x*256 + threadIdx.x;
  if (e < ET){
    int d = (e < EE) ? ei[EE + e] : (e - EE);
    rank[e] = atomicAdd(&cnt[d], 1);
  }
}

__global__ __launch_bounds__(256) void blocksum_k(const int* __restrict__ cnt,
                                                  int* __restrict__ bsum){
  int i = blockIdx.x*256 + threadIdx.x;
  int v = (i < NN) ? cnt[i] : 0;
  #pragma unroll
  for (int o=32;o;o>>=1) v += __shfl_xor(v,o);
  __shared__ int ws[4];
  if ((threadIdx.x & 63) == 0) ws[threadIdx.x>>6] = v;
  __syncthreads();
  if (threadIdx.x == 0) bsum[blockIdx.x] = ws[0]+ws[1]+ws[2]+ws[3];
}

__global__ __launch_bounds__(256) void scanb_k(int* __restrict__ bsum, int nb){
  int tid = threadIdx.x;
  int v = (tid < nb) ? bsum[tid] : 0;
  int lane = tid & 63, wv = tid >> 6;
  int s = v;
  #pragma unroll
  for (int o=1;o<64;o<<=1){ int t = __shfl_up(s,o); if (lane>=o) s += t; }
  __shared__ int ws[4];
  if (lane == 63) ws[wv] = s;
  __syncthreads();
  int woff = 0;
  for (int k=0;k<wv;++k) woff += ws[k];
  if (tid < nb) bsum[tid] = s - v + woff;   // exclusive prefix
}

__global__ __launch_bounds__(256) void scatter_k(const int* __restrict__ cnt,
                                                 const int* __restrict__ bsum,
                                                 int* __restrict__ row_start){
  int i = blockIdx.x*256 + threadIdx.x;
  int v = (i < NN) ? cnt[i] : 0;
  int lane = threadIdx.x & 63, wv = threadIdx.x >> 6;
  int s = v;
  #pragma unroll
  for (int o=1;o<64;o<<=1){ int t = __shfl_up(s,o); if (lane>=o) s += t; }
  __shared__ int ws[4];
  if (lane == 63) ws[wv] = s;
  __syncthreads();
  int woff = 0;
  for (int k=0;k<wv;++k) woff += ws[k];
  int off = s - v + woff + bsum[blockIdx.x];
  if (i < NN) row_start[i] = off;
  if (i == 0) row_start[NN] = ET;
}

// ---- phase A: partition (pos,src) pairs into fixed 4096-wide pos-buckets ----
__global__ __launch_bounds__(256) void partA_k(const int* __restrict__ ei,
                                               const int* __restrict__ rank,
                                               const int* __restrict__ row_start,
                                               int* __restrict__ bcur,
                                               uint2* __restrict__ stage){
  __shared__ uint2 lpairs[KB];          // 16 KB
  __shared__ int lcnt[256], lstart[256], lrun[256], gbase[256];
  __shared__ int ws[4];
  int tid = threadIdx.x;
  int base = blockIdx.x * KB;
  int nE = min(KB, ET - base);
  lcnt[tid] = 0;
  __syncthreads();
  u32 pos_r[KB/256]; u32 src_r[KB/256];
  #pragma unroll
  for (int i=0;i<KB/256;++i){
    int e = base + i*256 + tid;
    u32 p = 0xFFFFFFFFu, s = 0;
    if (e < ET){
      int d, sr;
      if (e < EE){ sr = ei[e]; d = ei[EE + e]; }
      else       { sr = e - EE; d = sr; }
      p = (u32)(row_start[d] + rank[e]);
      s = (u32)sr;
      atomicAdd(&lcnt[p >> 12], 1);
    }
    pos_r[i] = p; src_r[i] = s;
  }
  __syncthreads();
  int v = lcnt[tid];
  int lane = tid & 63, wv = tid >> 6;
  int s = v;
  #pragma unroll
  for (int o=1;o<64;o<<=1){ int t = __shfl_up(s,o); if (lane>=o) s += t; }
  if (lane == 63) ws[wv] = s;
  __syncthreads();
  int woff = 0;
  for (int k=0;k<wv;++k) woff += ws[k];
  int excl = s - v + woff;
  lstart[tid] = excl;
  lrun[tid]   = excl;
  gbase[tid]  = (tid < NBUK && v > 0) ? atomicAdd(&bcur[tid], v) : 0;
  __syncthreads();
  #pragma unroll
  for (int i=0;i<KB/256;++i){
    if (pos_r[i] != 0xFFFFFFFFu){
      int b = pos_r[i] >> 12;
      int slot = atomicAdd(&lrun[b], 1);
      lpairs[slot] = make_uint2(pos_r[i], src_r[i]);
    }
  }
  __syncthreads();
  for (int j = tid; j < nE; j += 256){
    uint2 pr = lpairs[j];
    int b = pr.x >> 12;
    int dest = (b << 12) + gbase[b] + (j - lstart[b]);
    stage[dest] = pr;
  }
}

// ---- phase B: assemble each 16KB srcs window in LDS, stream out coalesced ----
__global__ __launch_bounds__(256) void partB_k(const uint2* __restrict__ stage,
                                               int* __restrict__ srcs){
  __shared__ int buf[BSZ];              // 16 KB
  int b = blockIdx.x, tid = threadIdx.x;
  int base = b << 12;
  int n_b = min(BSZ, ET - base);
  for (int j = tid; j < n_b; j += 256){
    uint2 pr = stage[base + j];
    buf[pr.x - base] = (int)pr.y;
  }
  __syncthreads();
  for (int j = tid; j*4 < n_b; j += 256){
    *(int4*)(srcs + base + j*4) = *(const int4*)(buf + j*4);
  }
}

// ------- register-blocked GEMM: C[N,128] = A[N,128] @ W[128,128] ---------
// 64 rows/block, 256 threads, thread tile 4x8, K panels of 16, double-buffered
// small LDS. Fused rowdot epilogue (hs, hd f32-exact). Stores C as fp16.
__global__ __launch_bounds__(256) void gemm_rb_k(const float* __restrict__ A,
                                                 const float* __restrict__ W,
                                                 const float* __restrict__ as,
                                                 const float* __restrict__ ad,
                                                 u16* __restrict__ Ch,
                                                 float* __restrict__ hs,
                                                 float* __restrict__ hd){
  __shared__ float As[2][16][68];     // [buf][k][row], pad 68
  __shared__ float Wsh[2][16][128];   // [buf][k][col]
  int tid = threadIdx.x;
  int rbase = blockIdx.x*64;
  int ty = tid >> 4, tx = tid & 15;   // rows ty*4.., cols tx*8..
  int arow = tid >> 2, aq = tid & 3;  // A stage: row, k-quad
  int wk = tid >> 5, wc = tid & 31;   // W stage: k-row, col-quad

  float4 aReg, w0Reg, w1Reg;
  {
    int r = rbase + arow;
    aReg = (r < NN) ? *(const float4*)(A + (size_t)r*DD + aq*4) : float4{0,0,0,0};
    w0Reg = *(const float4*)(W + (size_t)wk*DD + wc*4);
    w1Reg = *(const float4*)(W + (size_t)(wk+8)*DD + wc*4);
  }
  As[0][aq*4+0][arow] = aReg.x;
  As[0][aq*4+1][arow] = aReg.y;
  As[0][aq*4+2][arow] = aReg.z;
  As[0][aq*4+3][arow] = aReg.w;
  *(float4*)(&Wsh[0][wk][wc*4])   = w0Reg;
  *(float4*)(&Wsh[0][wk+8][wc*4]) = w1Reg;
  __syncthreads();

  float acc[4][8] = {};
  for (int t=0; t<8; ++t){
    int cur = t & 1;
    if (t < 7){
      int k0 = (t+1)*16;
      int r = rbase + arow;
      aReg = (r < NN) ? *(const float4*)(A + (size_t)r*DD + k0 + aq*4) : float4{0,0,0,0};
      w0Reg = *(const float4*)(W + (size_t)(k0+wk)*DD + wc*4);
      w1Reg = *(const float4*)(W + (size_t)(k0+wk+8)*DD + wc*4);
    }
    #pragma unroll
    for (int k=0;k<16;++k){
      float4 a4  = *(const float4*)(&As[cur][k][ty*4]);
      float4 wA  = *(const float4*)(&Wsh[cur][k][tx*8]);
      float4 wB  = *(const float4*)(&Wsh[cur][k][tx*8+4]);
      float a[4] = {a4.x, a4.y, a4.z, a4.w};
      float wv[8] = {wA.x, wA.y, wA.z, wA.w, wB.x, wB.y, wB.z, wB.w};
      #pragma unroll
      for (int ii=0;ii<4;++ii)
        #pragma unroll
        for (int jj=0;jj<8;++jj)
          acc[ii][jj] += a[ii]*wv[jj];
    }
    if (t < 7){
      __syncthreads();
      int nxt = cur ^ 1;
      As[nxt][aq*4+0][arow] = aReg.x;
      As[nxt][aq*4+1][arow] = aReg.y;
      As[nxt][aq*4+2][arow] = aReg.z;
      As[nxt][aq*4+3][arow] = aReg.w;
      *(float4*)(&Wsh[nxt][wk][wc*4])   = w0Reg;
      *(float4*)(&Wsh[nxt][wk+8][wc*4]) = w1Reg;
      __syncthreads();
    }
  }

  // fused rowdot epilogue: hs/hd from f32 accumulators (alphas stay exact)
  float4 s0 = *(const float4*)(as + tx*8);
  float4 s1 = *(const float4*)(as + tx*8 + 4);
  float4 d0 = *(const float4*)(ad + tx*8);
  float4 d1 = *(const float4*)(ad + tx*8 + 4);
  #pragma unroll
  for (int ii=0;ii<4;++ii){
    float ds = acc[ii][0]*s0.x + acc[ii][1]*s0.y + acc[ii][2]*s0.z + acc[ii][3]*s0.w
             + acc[ii][4]*s1.x + acc[ii][5]*s1.y + acc[ii][6]*s1.z + acc[ii][7]*s1.w;
    float dd = acc[ii][0]*d0.x + acc[ii][1]*d0.y + acc[ii][2]*d0.z + acc[ii][3]*d0.w
             + acc[ii][4]*d1.x + acc[ii][5]*d1.y + acc[ii][6]*d1.z + acc[ii][7]*d1.w;
    #pragma unroll
    for (int o=1;o<16;o<<=1){ ds += __shfl_xor(ds,o); dd += __shfl_xor(dd,o); }
    int r = rbase + ty*4 + ii;
    if (tx == 0 && r < NN){ hs[r] = ds; hd[r] = dd; }
  }
  // C store (fp16)
  #pragma unroll
  for (int ii=0;ii<4;++ii){
    int r = rbase + ty*4 + ii;
    if (r < NN){
      ushort4 o0 = {f2h(acc[ii][0]), f2h(acc[ii][1]), f2h(acc[ii][2]), f2h(acc[ii][3])};
      ushort4 o1 = {f2h(acc[ii][4]), f2h(acc[ii][5]), f2h(acc[ii][6]), f2h(acc[ii][7])};
      *(ushort4*)(Ch + (size_t)r*DD + tx*8)     = o0;
      *(ushort4*)(Ch + (size_t)r*DD + tx*8 + 4) = o1;
    }
  }
}

// ---- agg (fp16 h): one wave per node, half-wave parity split.
// FROZEN round-8 text (known-good; do not restructure this loop).
__global__ __launch_bounds__(256) void gat_agg_h_k(const u16* __restrict__ hh,
                                                   const float* __restrict__ hs,
                                                   const float* __restrict__ hd,
                                                   const int* __restrict__ row_start,
                                                   const int* __restrict__ srcs,
                                                   const float* __restrict__ bias,
                                                   float* __restrict__ out){
  int node = blockIdx.x*4 + (threadIdx.x >> 6);
  int lane = threadIdx.x & 63;
  if (node >= NN) return;
  int half = lane >> 5;
  int hl   = lane & 31;
  int beg = row_start[node], end = row_start[node+1];
  float hdn = hd[node];
  float m = -INFINITY, denom = 0.f;
  float a0=0.f, a1=0.f, a2=0.f, a3=0.f;
  for (int c=beg; c<end; c+=64){
    int nc = min(64, end-c);
    float e = -INFINITY; int src = 0;
    if (lane < nc){
      src = srcs[c+lane];
      float t = hs[src] + hdn;
      e = (t >= 0.f) ? t : SLOPE*t;
    }
    float cm = e;
    #pragma unroll
    for (int o=32;o;o>>=1) cm = fmaxf(cm, __shfl_xor(cm,o));
    float nm = fmaxf(m, cm);
    float w = (lane < nc) ? expf(e - nm) : 0.f;
    float cs = w;
    #pragma unroll
    for (int o=32;o;o>>=1) cs += __shfl_xor(cs,o);
    float scale = expf(m - nm);
    denom = denom*scale + cs;
    a0 *= scale; a1 *= scale; a2 *= scale; a3 *= scale;
    m = nm;
    int nh = (nc + 1 - half) >> 1;
    for (int i=0;i<nh;++i){
      int j = 2*i + half;
      float wi = __shfl(w, j);
      int   si = __shfl(src, j);
      uint2 hv = *(const uint2*)(hh + (size_t)si*DD + hl*4);
      a0 += wi*hlo(hv.x); a1 += wi*hhi(hv.x);
      a2 += wi*hlo(hv.y); a3 += wi*hhi(hv.y);
    }
  }
  a0 += __shfl_xor(a0, 32);
  a1 += __shfl_xor(a1, 32);
  a2 += __shfl_xor(a2, 32);
  a3 += __shfl_xor(a3, 32);
  if (half == 0){
    float inv = 1.f/denom;
    float4 b4 = *(const float4*)(bias + hl*4);
    float4 o4;
    o4.x = fmaxf(a0*inv + b4.x, 0.f);
    o4.y = fmaxf(a1*inv + b4.y, 0.f);
    o4.z = fmaxf(a2*inv + b4.z, 0.f);
    o4.w = fmaxf(a3*inv + b4.w, 0.f);
    *(float4*)(out + (size_t)node*DD + hl*4) = o4;
  }
}

// ---- fused tail: pool + lin0 + lin1(+energy,residual) + lins + head -----
// FROZEN round-8 text.
__global__ __launch_bounds__(128) void tail_k(const float* __restrict__ h,
                                              const int* __restrict__ gstart,
                                              const float* __restrict__ energy,
                                              const float* __restrict__ W0, const float* __restrict__ b0,
                                              const float* __restrict__ W1, const float* __restrict__ b1,
                                              const float* __restrict__ W2, const float* __restrict__ b2,
                                              const float* __restrict__ W3, const float* __restrict__ b3,
                                              float* __restrict__ out){
  __shared__ float row[DD];
  __shared__ float buf[DD];
  int gr = blockIdx.x, j = threadIdx.x;
  int beg = gstart[gr], end = gstart[gr+1];
  float s = 0.f;
  for (int n=beg; n<end; ++n) s += h[(size_t)n*DD + j];
  row[j] = s;
  __syncthreads();
  float acc = 0.f;
  #pragma unroll 8
  for (int k=0;k<DD;++k) acc += row[k]*W0[k*DD + j];
  float y = fmaxf(acc + b0[j], 0.f);
  buf[j] = y;
  __syncthreads();
  acc = 0.f;
  #pragma unroll 8
  for (int k=0;k<DD;++k) acc += buf[k]*W1[k*DD + j];
  acc += energy[gr]*W1[DD*DD + j];
  float z = fmaxf(acc + b1[j], 0.f) + y;
  __syncthreads();
  row[j] = z;
  __syncthreads();
  acc = 0.f;
  #pragma unroll 8
  for (int k=0;k<DD;++k) acc += row[k]*W2[k*DD + j];
  float z2 = fmaxf(acc + b2[j], 0.f);
  buf[j] = z2;
  __syncthreads();
  if (j < 64){
    float za = buf[j], zb = buf[j+64];
    float l0 = za*W3[j*2]     + zb*W3[(j+64)*2];
    float l1 = za*W3[j*2 + 1] + zb*W3[(j+64)*2 + 1];
    #pragma unroll
    for (int o=32;o;o>>=1){ l0 += __shfl_xor(l0,o); l1 += __shfl_xor(l1,o); }
    if (j == 0){
      l0 += b3[0]; l1 += b3[1];
      float mx = fmaxf(l0, l1);
      float lse = mx + logf(expf(l0-mx) + expf(l1-mx));
      out[gr*2]   = l0 - lse;
      out[gr*2+1] = l1 - lse;
    }
  }
}

extern "C" void kernel_launch(void* const* d_in, const int* in_sizes, int n_in,
                              void* d_out, int out_size, void* d_ws, size_t ws_size,
                              hipStream_t stream) {
  const float* x      = (const float*)d_in[0];
  const float* energy = (const float*)d_in[1];
  const float* W1     = (const float*)d_in[2];
  const float* as1    = (const float*)d_in[3];
  const float* ad1    = (const float*)d_in[4];
  const float* b1     = (const float*)d_in[5];
  const float* Ws     = (const float*)d_in[6];
  const float* ass    = (const float*)d_in[7];
  const float* ads    = (const float*)d_in[8];
  const float* bs     = (const float*)d_in[9];
  const float* lin0_W = (const float*)d_in[10];
  const float* lin0_b = (const float*)d_in[11];
  const float* lin1_W = (const float*)d_in[12];
  const float* lin1_b = (const float*)d_in[13];
  const float* lins_W = (const float*)d_in[14];
  const float* lins_b = (const float*)d_in[15];
  const float* lin3_W = (const float*)d_in[16];
  const float* lin3_b = (const float*)d_in[17];
  const int*   ei     = (const int*)d_in[18];
  const int*   batchs = (const int*)d_in[19];
  float* out = (float*)d_out;

  char* wp = (char*)d_ws;
  auto alloc = [&](size_t bytes)->void*{
    void* p = (void*)wp;
    wp += (bytes + 255) & ~(size_t)255;
    return p;
  };
  float* hA        = (float*)alloc((size_t)NN*DD*4);   // agg output (f32)
  float* hB        = (float*)alloc((size_t)NN*DD*4);   // gemm out buffer
  u16*   hHf       = (u16*)hB;                         // fp16 view (all layers)
  float* hs        = (float*)alloc((size_t)NN*4);
  float* hd        = (float*)alloc((size_t)NN*4);
  int*   cnt       = (int*)alloc((size_t)NN*4);
  int*   row_start = (int*)alloc((size_t)(NN+1)*4);
  int*   rank      = (int*)alloc((size_t)ET*4);
  int*   srcs      = (int*)alloc((size_t)ET*4);
  uint2* stage     = (uint2*)alloc((size_t)NBUK*BSZ*8);
  int*   bcur      = (int*)alloc((size_t)NBUK*4);
  int*   gstart    = (int*)alloc((size_t)(GG+1)*4);
  int*   bsum      = (int*)alloc((size_t)256*4);

  const int NB_N  = (NN + 255)/256;     // 196
  const int NB_E  = (ET + 255)/256;     // 3321
  const int NB_W  = (NN + 3)/4;         // 12500 (wave per node)
  const int NB_G  = (NN + 63)/64;       // 782 gemm blocks

  // CSR + graph boundaries (two-phase bucketed scatter)
  init_k<<<NB_N, 256, 0, stream>>>(batchs, cnt, gstart, bcur);
  count_k<<<NB_E, 256, 0, stream>>>(ei, cnt, rank);
  blocksum_k<<<NB_N, 256, 0, stream>>>(cnt, bsum);
  scanb_k<<<1, 256, 0, stream>>>(bsum, NB_N);
  scatter_k<<<NB_N, 256, 0, stream>>>(cnt, bsum, row_start);
  partA_k<<<NBA, 256, 0, stream>>>(ei, rank, row_start, bcur, stage);
  partB_k<<<NBUK, 256, 0, stream>>>(stage, srcs);

  // 4 GAT layers, all on the fp16 gather path (alphas stay f32-exact)
  gemm_rb_k<<<NB_G, 256, 0, stream>>>(x, W1, as1, ad1, hHf, hs, hd);
  gat_agg_h_k<<<NB_W, 256, 0, stream>>>(hHf, hs, hd, row_start, srcs, b1, hA);
  for (int l=1; l<4; ++l){
    const float* Wl  = Ws  + (size_t)(l-1)*DD*DD;
    const float* asl = ass + (size_t)(l-1)*DD;
    const float* adl = ads + (size_t)(l-1)*DD;
    const float* bl  = bs  + (size_t)(l-1)*DD;
    gemm_rb_k<<<NB_G, 256, 0, stream>>>(hA, Wl, asl, adl, hHf, hs, hd);
    gat_agg_h_k<<<NB_W, 256, 0, stream>>>(hHf, hs, hd, row_start, srcs, bl, hA);
  }

  // fused tail
  tail_k<<<GG, 128, 0, stream>>>(hA, gstart, energy,
                                 lin0_W, lin0_b, lin1_W, lin1_b,
                                 lins_W, lins_b, lin3_W, lin3_b, out);
}

// Round 12
// 481.782 us; speedup vs baseline: 1.1569x; 1.0901x over previous
//
#include <hip/hip_runtime.h>
#include <math.h>

#define NN 50000
#define EE 800000
#define ET 850000   // EE + NN (self loops appended)
#define DD 128
#define GG 1000
#define SLOPE 0.2f

#define KB   2048          // edges per phase-A block
#define NBA  416           // ceil(ET/KB)
#define BSZ  4096          // positions per bucket
#define NBUK 208           // ceil(ET/BSZ)

#define LSTR 136           // LDS row stride in fp16 (16B-aligned, conflict-light)

typedef unsigned int  u32;
typedef unsigned short u16;
typedef _Float16 f16;
typedef __attribute__((ext_vector_type(8))) _Float16 f16x8;
typedef __attribute__((ext_vector_type(4))) float f32x4;

// fp16 pack/unpack (hardware cvt, round-to-nearest-even)
__device__ __forceinline__ u16 f2h(float f){
  return __builtin_bit_cast(unsigned short, (_Float16)f);
}
__device__ __forceinline__ float hlo(u32 d){
  return (float)__builtin_bit_cast(_Float16, (unsigned short)(d & 0xFFFFu));
}
__device__ __forceinline__ float hhi(u32 d){
  return (float)__builtin_bit_cast(_Float16, (unsigned short)(d >> 16));
}

// ---------------- init: cnt=0, bcur=0, graph boundaries ----------------
__global__ void init_k(const int* __restrict__ batchs, int* __restrict__ cnt,
                       int* __restrict__ gstart, int* __restrict__ bcur){
  int n = blockIdx.x*256 + threadIdx.x;
  if (n < NBUK) bcur[n] = 0;
  if (n < NN){
    cnt[n] = 0;
    int b = batchs[n];
    int prev = n ? batchs[n-1] : -1;
    for (int g = prev+1; g <= b; ++g) gstart[g] = n;
    if (n == NN-1){
      for (int g = b+1; g <= GG; ++g) gstart[g] = NN;
    }
  }
}

// count + per-edge rank (atomicAdd return)
__global__ void count_k(const int* __restrict__ ei, int* __restrict__ cnt,
                        int* __restrict__ rank){
  int e = blockIdx.x*256 + threadIdx.x;
  if (e < ET){
    int d = (e < EE) ? ei[EE + e] : (e - EE);
    rank[e] = atomicAdd(&cnt[d], 1);
  }
}

__global__ __launch_bounds__(256) void blocksum_k(const int* __restrict__ cnt,
                                                  int* __restrict__ bsum){
  int i = blockIdx.x*256 + threadIdx.x;
  int v = (i < NN) ? cnt[i] : 0;
  #pragma unroll
  for (int o=32;o;o>>=1) v += __shfl_xor(v,o);
  __shared__ int ws[4];
  if ((threadIdx.x & 63) == 0) ws[threadIdx.x>>6] = v;
  __syncthreads();
  if (threadIdx.x == 0) bsum[blockIdx.x] = ws[0]+ws[1]+ws[2]+ws[3];
}

__global__ __launch_bounds__(256) void scanb_k(int* __restrict__ bsum, int nb){
  int tid = threadIdx.x;
  int v = (tid < nb) ? bsum[tid] : 0;
  int lane = tid & 63, wv = tid >> 6;
  int s = v;
  #pragma unroll
  for (int o=1;o<64;o<<=1){ int t = __shfl_up(s,o); if (lane>=o) s += t; }
  __shared__ int ws[4];
  if (lane == 63) ws[wv] = s;
  __syncthreads();
  int woff = 0;
  for (int k=0;k<wv;++k) woff += ws[k];
  if (tid < nb) bsum[tid] = s - v + woff;   // exclusive prefix
}

__global__ __launch_bounds__(256) void scatter_k(const int* __restrict__ cnt,
                                                 const int* __restrict__ bsum,
                                                 int* __restrict__ row_start){
  int i = blockIdx.x*256 + threadIdx.x;
  int v = (i < NN) ? cnt[i] : 0;
  int lane = threadIdx.x & 63, wv = threadIdx.x >> 6;
  int s = v;
  #pragma unroll
  for (int o=1;o<64;o<<=1){ int t = __shfl_up(s,o); if (lane>=o) s += t; }
  __shared__ int ws[4];
  if (lane == 63) ws[wv] = s;
  __syncthreads();
  int woff = 0;
  for (int k=0;k<wv;++k) woff += ws[k];
  int off = s - v + woff + bsum[blockIdx.x];
  if (i < NN) row_start[i] = off;
  if (i == 0) row_start[NN] = ET;
}

// ---- phase A: partition (pos,src) pairs into fixed 4096-wide pos-buckets ----
__global__ __launch_bounds__(256) void partA_k(const int* __restrict__ ei,
                                               const int* __restrict__ rank,
                                               const int* __restrict__ row_start,
                                               int* __restrict__ bcur,
                                               uint2* __restrict__ stage){
  __shared__ uint2 lpairs[KB];          // 16 KB
  __shared__ int lcnt[256], lstart[256], lrun[256], gbase[256];
  __shared__ int ws[4];
  int tid = threadIdx.x;
  int base = blockIdx.x * KB;
  int nE = min(KB, ET - base);
  lcnt[tid] = 0;
  __syncthreads();
  u32 pos_r[KB/256]; u32 src_r[KB/256];
  #pragma unroll
  for (int i=0;i<KB/256;++i){
    int e = base + i*256 + tid;
    u32 p = 0xFFFFFFFFu, s = 0;
    if (e < ET){
      int d, sr;
      if (e < EE){ sr = ei[e]; d = ei[EE + e]; }
      else       { sr = e - EE; d = sr; }
      p = (u32)(row_start[d] + rank[e]);
      s = (u32)sr;
      atomicAdd(&lcnt[p >> 12], 1);
    }
    pos_r[i] = p; src_r[i] = s;
  }
  __syncthreads();
  int v = lcnt[tid];
  int lane = tid & 63, wv = tid >> 6;
  int s = v;
  #pragma unroll
  for (int o=1;o<64;o<<=1){ int t = __shfl_up(s,o); if (lane>=o) s += t; }
  if (lane == 63) ws[wv] = s;
  __syncthreads();
  int woff = 0;
  for (int k=0;k<wv;++k) woff += ws[k];
  int excl = s - v + woff;
  lstart[tid] = excl;
  lrun[tid]   = excl;
  gbase[tid]  = (tid < NBUK && v > 0) ? atomicAdd(&bcur[tid], v) : 0;
  __syncthreads();
  #pragma unroll
  for (int i=0;i<KB/256;++i){
    if (pos_r[i] != 0xFFFFFFFFu){
      int b = pos_r[i] >> 12;
      int slot = atomicAdd(&lrun[b], 1);
      lpairs[slot] = make_uint2(pos_r[i], src_r[i]);
    }
  }
  __syncthreads();
  for (int j = tid; j < nE; j += 256){
    uint2 pr = lpairs[j];
    int b = pr.x >> 12;
    int dest = (b << 12) + gbase[b] + (j - lstart[b]);
    stage[dest] = pr;
  }
}

// ---- phase B: assemble each 16KB srcs window in LDS, stream out coalesced ----
__global__ __launch_bounds__(256) void partB_k(const uint2* __restrict__ stage,
                                               int* __restrict__ srcs){
  __shared__ int buf[BSZ];              // 16 KB
  int b = blockIdx.x, tid = threadIdx.x;
  int base = b << 12;
  int n_b = min(BSZ, ET - base);
  for (int j = tid; j < n_b; j += 256){
    uint2 pr = stage[base + j];
    buf[pr.x - base] = (int)pr.y;
  }
  __syncthreads();
  for (int j = tid; j*4 < n_b; j += 256){
    *(int4*)(srcs + base + j*4) = *(const int4*)(buf + j*4);
  }
}

// ------- MFMA GEMM: Ch[N,128](fp16) = A[N,128](f32->fp16) @ W[128,128] ---
// 64 rows/block, 256 threads = 4 waves; each wave owns 16 rows x 128 cols.
// A and W^T staged in LDS as fp16 (stride LSTR). v_mfma_f32_16x16x32_f16,
// f32 accumulate; fused rowdot epilogue gives hs/hd from f32 accumulators.
__global__ __launch_bounds__(256) void gemm_mfma_k(const float* __restrict__ A,
                                                   const float* __restrict__ W,
                                                   const float* __restrict__ as,
                                                   const float* __restrict__ ad,
                                                   u16* __restrict__ Ch,
                                                   float* __restrict__ hs,
                                                   float* __restrict__ hd){
  __shared__ u16 Al[64*LSTR];    // A tile  [r][k]   17 KB
  __shared__ u16 Wt[128*LSTR];   // W^T     [n][k]   34 KB
  int tid = threadIdx.x;
  int rbase = blockIdx.x*64;

  // stage A (f32 -> fp16): 64x128 = 2048 float4, 8 per thread
  #pragma unroll
  for (int it=0; it<8; ++it){
    int i = it*256 + tid;
    int r = i >> 5, c4 = i & 31;
    float4 v = {0.f,0.f,0.f,0.f};
    if (rbase + r < NN) v = *(const float4*)(A + (size_t)(rbase+r)*DD + c4*4);
    u32 p0 = (u32)f2h(v.x) | ((u32)f2h(v.y) << 16);
    u32 p1 = (u32)f2h(v.z) | ((u32)f2h(v.w) << 16);
    *(u32*)(&Al[r*LSTR + c4*4])     = p0;
    *(u32*)(&Al[r*LSTR + c4*4 + 2]) = p1;
  }
  // stage W transposed (f32 -> fp16): 128x128 = 4096 float4, 16 per thread
  #pragma unroll
  for (int it=0; it<16; ++it){
    int i = it*256 + tid;
    int k = i >> 5, c4 = i & 31;
    float4 v = *(const float4*)(W + (size_t)k*DD + c4*4);
    Wt[(c4*4+0)*LSTR + k] = f2h(v.x);
    Wt[(c4*4+1)*LSTR + k] = f2h(v.y);
    Wt[(c4*4+2)*LSTR + k] = f2h(v.z);
    Wt[(c4*4+3)*LSTR + k] = f2h(v.w);
  }
  __syncthreads();

  int wid = tid >> 6;        // wave id: rows [wid*16, wid*16+16)
  int l   = tid & 63;
  int lr  = l & 15;          // A row / B col within 16
  int lk  = l >> 4;          // k-group (8 fp16 each)

  f32x4 acc[8] = {};
  #pragma unroll
  for (int ks=0; ks<4; ++ks){
    int k0 = ks*32;
    f16x8 a = *(const f16x8*)(&Al[(wid*16+lr)*LSTR + k0 + lk*8]);
    #pragma unroll
    for (int ct=0; ct<8; ++ct){
      f16x8 b = *(const f16x8*)(&Wt[(ct*16+lr)*LSTR + k0 + lk*8]);
      acc[ct] = __builtin_amdgcn_mfma_f32_16x16x32_f16(a, b, acc[ct], 0, 0, 0);
    }
  }

  // lane holds C[r][c] = acc[ct][i], r = rbase+wid*16+lk*4+i, c = ct*16+lr
  float hsum[4] = {0.f,0.f,0.f,0.f};
  float hdsum[4] = {0.f,0.f,0.f,0.f};
  #pragma unroll
  for (int ct=0; ct<8; ++ct){
    float a_s = as[ct*16 + lr];
    float a_d = ad[ct*16 + lr];
    #pragma unroll
    for (int i=0;i<4;++i){
      hsum[i]  += acc[ct][i]*a_s;
      hdsum[i] += acc[ct][i]*a_d;
    }
  }
  #pragma unroll
  for (int i=0;i<4;++i){
    #pragma unroll
    for (int o=1;o<16;o<<=1){
      hsum[i]  += __shfl_xor(hsum[i],  o);
      hdsum[i] += __shfl_xor(hdsum[i], o);
    }
  }
  if (lr == 0){
    #pragma unroll
    for (int i=0;i<4;++i){
      int r = rbase + wid*16 + lk*4 + i;
      if (r < NN){ hs[r] = hsum[i]; hd[r] = hdsum[i]; }
    }
  }
  // C store (fp16)
  #pragma unroll
  for (int i=0;i<4;++i){
    int r = rbase + wid*16 + lk*4 + i;
    if (r < NN){
      #pragma unroll
      for (int ct=0; ct<8; ++ct)
        Ch[(size_t)r*DD + ct*16 + lr] = f2h(acc[ct][i]);
    }
  }
}

// ---- agg (fp16 h): one wave per node, half-wave parity split.
// FROZEN round-8 text (known-good; do not restructure this loop).
__global__ __launch_bounds__(256) void gat_agg_h_k(const u16* __restrict__ hh,
                                                   const float* __restrict__ hs,
                                                   const float* __restrict__ hd,
                                                   const int* __restrict__ row_start,
                                                   const int* __restrict__ srcs,
                                                   const float* __restrict__ bias,
                                                   float* __restrict__ out){
  int node = blockIdx.x*4 + (threadIdx.x >> 6);
  int lane = threadIdx.x & 63;
  if (node >= NN) return;
  int half = lane >> 5;
  int hl   = lane & 31;
  int beg = row_start[node], end = row_start[node+1];
  float hdn = hd[node];
  float m = -INFINITY, denom = 0.f;
  float a0=0.f, a1=0.f, a2=0.f, a3=0.f;
  for (int c=beg; c<end; c+=64){
    int nc = min(64, end-c);
    float e = -INFINITY; int src = 0;
    if (lane < nc){
      src = srcs[c+lane];
      float t = hs[src] + hdn;
      e = (t >= 0.f) ? t : SLOPE*t;
    }
    float cm = e;
    #pragma unroll
    for (int o=32;o;o>>=1) cm = fmaxf(cm, __shfl_xor(cm,o));
    float nm = fmaxf(m, cm);
    float w = (lane < nc) ? expf(e - nm) : 0.f;
    float cs = w;
    #pragma unroll
    for (int o=32;o;o>>=1) cs += __shfl_xor(cs,o);
    float scale = expf(m - nm);
    denom = denom*scale + cs;
    a0 *= scale; a1 *= scale; a2 *= scale; a3 *= scale;
    m = nm;
    int nh = (nc + 1 - half) >> 1;
    for (int i=0;i<nh;++i){
      int j = 2*i + half;
      float wi = __shfl(w, j);
      int   si = __shfl(src, j);
      uint2 hv = *(const uint2*)(hh + (size_t)si*DD + hl*4);
      a0 += wi*hlo(hv.x); a1 += wi*hhi(hv.x);
      a2 += wi*hlo(hv.y); a3 += wi*hhi(hv.y);
    }
  }
  a0 += __shfl_xor(a0, 32);
  a1 += __shfl_xor(a1, 32);
  a2 += __shfl_xor(a2, 32);
  a3 += __shfl_xor(a3, 32);
  if (half == 0){
    float inv = 1.f/denom;
    float4 b4 = *(const float4*)(bias + hl*4);
    float4 o4;
    o4.x = fmaxf(a0*inv + b4.x, 0.f);
    o4.y = fmaxf(a1*inv + b4.y, 0.f);
    o4.z = fmaxf(a2*inv + b4.z, 0.f);
    o4.w = fmaxf(a3*inv + b4.w, 0.f);
    *(float4*)(out + (size_t)node*DD + hl*4) = o4;
  }
}

// ---- fused tail: pool + lin0 + lin1(+energy,residual) + lins + head -----
// FROZEN round-8 text.
__global__ __launch_bounds__(128) void tail_k(const float* __restrict__ h,
                                              const int* __restrict__ gstart,
                                              const float* __restrict__ energy,
                                              const float* __restrict__ W0, const float* __restrict__ b0,
                                              const float* __restrict__ W1, const float* __restrict__ b1,
                                              const float* __restrict__ W2, const float* __restrict__ b2,
                                              const float* __restrict__ W3, const float* __restrict__ b3,
                                              float* __restrict__ out){
  __shared__ float row[DD];
  __shared__ float buf[DD];
  int gr = blockIdx.x, j = threadIdx.x;
  int beg = gstart[gr], end = gstart[gr+1];
  float s = 0.f;
  for (int n=beg; n<end; ++n) s += h[(size_t)n*DD + j];
  row[j] = s;
  __syncthreads();
  float acc = 0.f;
  #pragma unroll 8
  for (int k=0;k<DD;++k) acc += row[k]*W0[k*DD + j];
  float y = fmaxf(acc + b0[j], 0.f);
  buf[j] = y;
  __syncthreads();
  acc = 0.f;
  #pragma unroll 8
  for (int k=0;k<DD;++k) acc += buf[k]*W1[k*DD + j];
  acc += energy[gr]*W1[DD*DD + j];
  float z = fmaxf(acc + b1[j], 0.f) + y;
  __syncthreads();
  row[j] = z;
  __syncthreads();
  acc = 0.f;
  #pragma unroll 8
  for (int k=0;k<DD;++k) acc += row[k]*W2[k*DD + j];
  float z2 = fmaxf(acc + b2[j], 0.f);
  buf[j] = z2;
  __syncthreads();
  if (j < 64){
    float za = buf[j], zb = buf[j+64];
    float l0 = za*W3[j*2]     + zb*W3[(j+64)*2];
    float l1 = za*W3[j*2 + 1] + zb*W3[(j+64)*2 + 1];
    #pragma unroll
    for (int o=32;o;o>>=1){ l0 += __shfl_xor(l0,o); l1 += __shfl_xor(l1,o); }
    if (j == 0){
      l0 += b3[0]; l1 += b3[1];
      float mx = fmaxf(l0, l1);
      float lse = mx + logf(expf(l0-mx) + expf(l1-mx));
      out[gr*2]   = l0 - lse;
      out[gr*2+1] = l1 - lse;
    }
  }
}

extern "C" void kernel_launch(void* const* d_in, const int* in_sizes, int n_in,
                              void* d_out, int out_size, void* d_ws, size_t ws_size,
                              hipStream_t stream) {
  const float* x      = (const float*)d_in[0];
  const float* energy = (const float*)d_in[1];
  const float* W1     = (const float*)d_in[2];
  const float* as1    = (const float*)d_in[3];
  const float* ad1    = (const float*)d_in[4];
  const float* b1     = (const float*)d_in[5];
  const float* Ws     = (const float*)d_in[6];
  const float* ass    = (const float*)d_in[7];
  const float* ads    = (const float*)d_in[8];
  const float* bs     = (const float*)d_in[9];
  const float* lin0_W = (const float*)d_in[10];
  const float* lin0_b = (const float*)d_in[11];
  const float* lin1_W = (const float*)d_in[12];
  const float* lin1_b = (const float*)d_in[13];
  const float* lins_W = (const float*)d_in[14];
  const float* lins_b = (const float*)d_in[15];
  const float* lin3_W = (const float*)d_in[16];
  const float* lin3_b = (const float*)d_in[17];
  const int*   ei     = (const int*)d_in[18];
  const int*   batchs = (const int*)d_in[19];
  float* out = (float*)d_out;

  char* wp = (char*)d_ws;
  auto alloc = [&](size_t bytes)->void*{
    void* p = (void*)wp;
    wp += (bytes + 255) & ~(size_t)255;
    return p;
  };
  float* hA        = (float*)alloc((size_t)NN*DD*4);   // agg output (f32)
  float* hB        = (float*)alloc((size_t)NN*DD*4);   // gemm out buffer
  u16*   hHf       = (u16*)hB;                         // fp16 view (all layers)
  float* hs        = (float*)alloc((size_t)NN*4);
  float* hd        = (float*)alloc((size_t)NN*4);
  int*   cnt       = (int*)alloc((size_t)NN*4);
  int*   row_start = (int*)alloc((size_t)(NN+1)*4);
  int*   rank      = (int*)alloc((size_t)ET*4);
  int*   srcs      = (int*)alloc((size_t)ET*4);
  uint2* stage     = (uint2*)alloc((size_t)NBUK*BSZ*8);
  int*   bcur      = (int*)alloc((size_t)NBUK*4);
  int*   gstart    = (int*)alloc((size_t)(GG+1)*4);
  int*   bsum      = (int*)alloc((size_t)256*4);

  const int NB_N  = (NN + 255)/256;     // 196
  const int NB_E  = (ET + 255)/256;     // 3321
  const int NB_W  = (NN + 3)/4;         // 12500 (wave per node)
  const int NB_G  = (NN + 63)/64;       // 782 gemm blocks

  // CSR + graph boundaries (two-phase bucketed scatter)
  init_k<<<NB_N, 256, 0, stream>>>(batchs, cnt, gstart, bcur);
  count_k<<<NB_E, 256, 0, stream>>>(ei, cnt, rank);
  blocksum_k<<<NB_N, 256, 0, stream>>>(cnt, bsum);
  scanb_k<<<1, 256, 0, stream>>>(bsum, NB_N);
  scatter_k<<<NB_N, 256, 0, stream>>>(cnt, bsum, row_start);
  partA_k<<<NBA, 256, 0, stream>>>(ei, rank, row_start, bcur, stage);
  partB_k<<<NBUK, 256, 0, stream>>>(stage, srcs);

  // 4 GAT layers, MFMA GEMM + fp16 gather (alphas f32 from MFMA accumulators)
  gemm_mfma_k<<<NB_G, 256, 0, stream>>>(x, W1, as1, ad1, hHf, hs, hd);
  gat_agg_h_k<<<NB_W, 256, 0, stream>>>(hHf, hs, hd, row_start, srcs, b1, hA);
  for (int l=1; l<4; ++l){
    const float* Wl  = Ws  + (size_t)(l-1)*DD*DD;
    const float* asl = ass + (size_t)(l-1)*DD;
    const float* adl = ads + (size_t)(l-1)*DD;
    const float* bl  = bs  + (size_t)(l-1)*DD;
    gemm_mfma_k<<<NB_G, 256, 0, stream>>>(hA, Wl, asl, adl, hHf, hs, hd);
    gat_agg_h_k<<<NB_W, 256, 0, stream>>>(hHf, hs, hd, row_start, srcs, bl, hA);
  }

  // fused tail
  tail_k<<<GG, 128, 0, stream>>>(hA, gstart, energy,
                                 lin0_W, lin0_b, lin1_W, lin1_b,
                                 lins_W, lins_b, lin3_W, lin3_b, out);
}